// Round 5
// baseline (82.094 us; speedup 1.0000x reference)
//
#include <hip/hip_runtime.h>

// NBCModel: non-backtracking closed-walk signature + MLP.
// B[i,j] = (dst_j == src_i) && (src_j != dst_i).  sig[g,k] = sum over edges i
// in graph g of diag(B^{k+1})_i.  out[g] = relu(sig @ W1 + b1) @ W2 + b2.
//
// R1 DFS ~105us. R2 level-BFS ~38us. R3 ballot atomics: neutral. R4 16 waves +
// 1-ds_read expansion: kernel ~25-30us — single-CU serial-phase latency.
// R5: 3-kernel split. K1 (1 blk) builds enriched CSR + level-0 frontier
// (+graph id packed in entry) into d_ws; K2 (32 blks) BFS over 64-start
// slices, CSR in LDS, global-atomic sig; K3 MLP (identical math to R4).

constexpr int E_EDGES  = 2048;
constexpr int L_WALK   = 8;
constexpr int G_GRAPHS = 128;
constexpr int HID      = 128;
constexpr int N_NODES  = 4096;
constexpr int NB_BLOCKS = 32;
constexpr int SLICE     = E_EDGES / NB_BLOCKS;  // 64 start edges per block
constexpr int CAP       = 1024;                 // per-slice frontier cap (~30x headroom)

// d_ws layout: f0 u64[2048] @0 | ebkt u64[2048] @16384 | sig i32[1024] @32768

// Bucket entry q: b(0:11) | src(11:23) | dst(23:35) | lo(35:47) | hi(47:59)
// Frontier entry e: s(0:11) | dst_cur(11:23) | lo(23:35) | hi(35:47) | g(47:54)
// Push: e2 = s | ((q>>23)&0xFFFFFFFFF)<<11 | (e & g-bits)   -- one ds_read_b64/trip.

__launch_bounds__(1024, 1)
__global__ void k1_build(const int* __restrict__ edge_index,
                         const int* __restrict__ edge_graph,
                         unsigned long long* __restrict__ f0,
                         unsigned long long* __restrict__ ebkt,
                         int* __restrict__ sig)
{
    __shared__ int s_cnt[N_NODES];
    __shared__ unsigned short s_off[N_NODES + 1];
    __shared__ int s_wavep[16];

    const int t    = threadIdx.x;
    const int lane = t & 63;
    const int wave = t >> 6;
    const int* src = edge_index;
    const int* dst = edge_index + E_EDGES;

    for (int n = t; n < N_NODES; n += 1024) s_cnt[n] = 0;
    sig[t] = 0;                                   // G*L == 1024, re-zero poisoned ws
    __syncthreads();

    // each thread owns edges t and t+1024; keep fields in registers
    const int se0 = src[t],        de0 = dst[t];
    const int se1 = src[t + 1024], de1 = dst[t + 1024];
    const int g0  = edge_graph[t], g1  = edge_graph[t + 1024];
    atomicAdd(&s_cnt[de0], 1);
    atomicAdd(&s_cnt[de1], 1);
    __syncthreads();

    // exclusive scan of 4096 counts, 4/thread
    const int base4 = t * 4;
    int loc[4];
    int run = 0;
    #pragma unroll
    for (int j = 0; j < 4; ++j) { loc[j] = run; run += s_cnt[base4 + j]; }
    int incl = run;
    #pragma unroll
    for (int off = 1; off < 64; off <<= 1) {
        int v = __shfl_up(incl, off);
        if (lane >= off) incl += v;
    }
    if (lane == 63) s_wavep[wave] = incl;
    __syncthreads();
    int wbase = 0;
    for (int w = 0; w < wave; ++w) wbase += s_wavep[w];
    const int start = wbase + incl - run;
    #pragma unroll
    for (int j = 0; j < 4; ++j) s_off[base4 + j] = (unsigned short)(start + loc[j]);
    if (t == 0) s_off[N_NODES] = (unsigned short)E_EDGES;
    __syncthreads();                              // s_off done; s_cnt reads done

    for (int n = t; n < N_NODES; n += 1024) s_cnt[n] = s_off[n];  // cursors
    __syncthreads();

    // fill enriched bucket (global scatter) + level-0 frontier (coalesced)
    {
        int p0 = atomicAdd(&s_cnt[de0], 1);
        ebkt[p0] = (unsigned long long)t
                 | ((unsigned long long)se0 << 11)
                 | ((unsigned long long)de0 << 23)
                 | ((unsigned long long)s_off[se0]     << 35)
                 | ((unsigned long long)s_off[se0 + 1] << 47);
        f0[t] = (unsigned long long)t
              | ((unsigned long long)de0 << 11)
              | ((unsigned long long)s_off[se0]     << 23)
              | ((unsigned long long)s_off[se0 + 1] << 35)
              | ((unsigned long long)g0 << 47);
    }
    {
        int e1 = t + 1024;
        int p1 = atomicAdd(&s_cnt[de1], 1);
        ebkt[p1] = (unsigned long long)e1
                 | ((unsigned long long)se1 << 11)
                 | ((unsigned long long)de1 << 23)
                 | ((unsigned long long)s_off[se1]     << 35)
                 | ((unsigned long long)s_off[se1 + 1] << 47);
        f0[e1] = (unsigned long long)e1
               | ((unsigned long long)de1 << 11)
               | ((unsigned long long)s_off[se1]     << 23)
               | ((unsigned long long)s_off[se1 + 1] << 35)
               | ((unsigned long long)g1 << 47);
    }
}

__launch_bounds__(256, 1)
__global__ void k2_bfs(const unsigned long long* __restrict__ f0,
                       const unsigned long long* __restrict__ ebkt,
                       int* __restrict__ sig)
{
    __shared__ unsigned long long s_eb[E_EDGES];   // 16 KB bucket copy
    __shared__ unsigned long long bufA[CAP];
    __shared__ unsigned long long bufB[CAP];
    __shared__ int s_nn[L_WALK + 1];

    const int t    = threadIdx.x;
    const int lane = t & 63;

    // stage bucket: 2048 u64 as 1024 x ulonglong2, 4 per thread, coalesced
    const ulonglong2* g2 = (const ulonglong2*)ebkt;
    ulonglong2*       s2 = (ulonglong2*)s_eb;
    #pragma unroll
    for (int i = 0; i < 4; ++i) s2[t + 256 * i] = g2[t + 256 * i];
    if (t < SLICE) bufA[t] = f0[blockIdx.x * SLICE + t];
    if (t <= L_WALK) s_nn[t] = (t == 0) ? SLICE : 0;
    __syncthreads();

    unsigned long long* cur = bufA;
    unsigned long long* nxt = bufB;
    for (int d = 0; d < L_WALK; ++d) {
        int n_cur = s_nn[d];
        if (n_cur > CAP) n_cur = CAP;
        for (int idx = t; idx < n_cur; idx += 256) {
            unsigned long long e = cur[idx];
            int s   = (int)( e        & 0x7FF);
            int dcc = (int)((e >> 11) & 0xFFF);
            int lo  = (int)((e >> 23) & 0xFFF);
            int hi  = (int)((e >> 35) & 0xFFF);
            unsigned long long gbits = e & (0x7Full << 47);
            for (int p = lo; p < hi; ++p) {
                unsigned long long q = s_eb[p];
                if ((int)((q >> 11) & 0xFFF) != dcc) {          // non-backtracking
                    int b = (int)(q & 0x7FF);
                    if (b == s)
                        atomicAdd(&sig[(int)(gbits >> 47) * L_WALK + d], 1);
                    if (d < L_WALK - 1) {
                        unsigned long long e2 = (unsigned long long)s
                            | (((q >> 23) & 0xFFFFFFFFFull) << 11) | gbits;
                        unsigned long long m = __ballot(1);
                        int leader = __ffsll(m) - 1;
                        int rank   = __popcll(m & ((1ull << lane) - 1ull));
                        int bpos = 0;
                        if (lane == leader) bpos = atomicAdd(&s_nn[d + 1], (int)__popcll(m));
                        bpos = __shfl(bpos, leader);
                        if (bpos + rank < CAP) nxt[bpos + rank] = e2;
                    }
                }
            }
        }
        unsigned long long* tmp = cur; cur = nxt; nxt = tmp;
        __syncthreads();
    }
}

__launch_bounds__(1024, 1)
__global__ void k3_mlp(const int* __restrict__ sig,
                       const float* __restrict__ W1,
                       const float* __restrict__ b1,
                       const float* __restrict__ W2,
                       const float* __restrict__ b2,
                       float* __restrict__ out)
{
    __shared__ float s_part[1024];
    const int t   = threadIdx.x;
    const int g   = t >> 3;
    const int sub = t & 7;

    float sv[L_WALK];
    #pragma unroll
    for (int k = 0; k < L_WALK; ++k) sv[k] = (float)sig[g * L_WALK + k];
    float o = 0.0f;
    const int j0 = sub * 16;
    #pragma unroll 4
    for (int jj = 0; jj < 16; ++jj) {
        int j = j0 + jj;
        float a = b1[j];
        #pragma unroll
        for (int k = 0; k < L_WALK; ++k) a += sv[k] * W1[k * HID + j];
        o += fmaxf(a, 0.0f) * W2[j];
    }
    s_part[t] = o;
    __syncthreads();
    if (t < G_GRAPHS) {
        float r = b2[0];
        #pragma unroll
        for (int s = 0; s < 8; ++s) r += s_part[t * 8 + s];
        out[t] = r;
    }
}

extern "C" void kernel_launch(void* const* d_in, const int* in_sizes, int n_in,
                              void* d_out, int out_size, void* d_ws, size_t ws_size,
                              hipStream_t stream) {
    const int*   edge_index = (const int*)d_in[0];
    const int*   edge_graph = (const int*)d_in[1];
    const float* W1 = (const float*)d_in[2];
    const float* b1 = (const float*)d_in[3];
    const float* W2 = (const float*)d_in[4];
    const float* b2 = (const float*)d_in[5];
    float* out = (float*)d_out;

    char* ws = (char*)d_ws;
    unsigned long long* f0   = (unsigned long long*)(ws);
    unsigned long long* ebkt = (unsigned long long*)(ws + 16384);
    int*                sig  = (int*)(ws + 32768);

    k1_build<<<1, 1024, 0, stream>>>(edge_index, edge_graph, f0, ebkt, sig);
    k2_bfs<<<NB_BLOCKS, 256, 0, stream>>>(f0, ebkt, sig);
    k3_mlp<<<1, 1024, 0, stream>>>(sig, W1, b1, W2, b2, out);
}

// Round 6
// 73.752 us; speedup vs baseline: 1.1131x; 1.1131x over previous
//
#include <hip/hip_runtime.h>

// NBCModel: non-backtracking closed-walk signature + MLP.
// B[i,j] = (dst_j == src_i) && (src_j != dst_i).  sig[g,k] = sum over edges i
// in graph g of diag(B^{k+1})_i.  out[g] = relu(sig @ W1 + b1) @ W2 + b2.
//
// R1 DFS 105us; R2 BFS ~38us; R3 ballot: neutral; R4 16-wave 1-ds_read: 81.4
// total; R5 3-kernel split: 82.1 (neutral -> graph-node overhead ~3us/node,
// BFS exec was NOT the cost; build + reset chain dominate).
// R6: single kernel (1 node). Linked-list adjacency via atomicExch (no scan,
// 3 build phases vs 6), node u64 = (src,dst,head[src],next) so expansion is
// one ds_read_b64; weights prefetched to LDS at start; MLP math identical R4.

constexpr int E_EDGES  = 2048;
constexpr int L_WALK   = 8;
constexpr int G_GRAPHS = 128;
constexpr int HID      = 128;
constexpr int N_NODES  = 4096;
constexpr int BLOCK    = 1024;
constexpr int CAP      = 2048;   // frontier cap; level0 = 2048, levels shrink (R4 exact)

typedef unsigned long long u64;

__launch_bounds__(BLOCK, 1)
__global__ void nbc_all(const int* __restrict__ edge_index,
                        const int* __restrict__ edge_graph,
                        const float* __restrict__ W1,
                        const float* __restrict__ b1,
                        const float* __restrict__ W2,
                        const float* __restrict__ b2,
                        float* __restrict__ out)
{
    // node entry q: src(0:12) | dst(12:24) | hs=head[src](24:36) | next(36:48)
    // frontier  e: s(0:11) | dst_cur(11:23) | ptr(23:35) | g(35:42)
    // push: e2 = s | ((q>>12)&0xFFFFFF)<<11 | gbits    (one ds_read_b64/step)
    __shared__ u64 s_bufA[CAP];            // frontier ping; aliased as head[4096] (int)
    __shared__ u64 s_bufB[CAP];            // frontier pong
    __shared__ u64 s_node[E_EDGES];        // enriched node entries; aliased s_part later
    __shared__ int s_sig[G_GRAPHS * L_WALK];
    __shared__ int s_nn[L_WALK + 1];
    __shared__ float s_W1[L_WALK * HID];
    __shared__ float s_b1[HID];
    __shared__ float s_W2[HID];
    __shared__ float s_b2;

    int* s_head = (int*)s_bufA;            // 4096 ints == 2048 u64 (exact alias)

    const int t    = threadIdx.x;
    const int lane = t & 63;

    // ---- phase 1: issue all global loads early; init LDS ----
    const int2 se2 = ((const int2*)edge_index)[t];             // src of edges 2t,2t+1
    const int2 de2 = ((const int2*)(edge_index + E_EDGES))[t]; // dst of edges 2t,2t+1
    const int2 ge2 = ((const int2*)edge_graph)[t];             // graph ids
    s_W1[t] = W1[t];                        // L_WALK*HID == 1024, one per thread
    if (t < HID) { s_b1[t] = b1[t]; s_W2[t] = W2[t]; }
    if (t == 0) s_b2 = b2[0];
    s_sig[t] = 0;                           // G*L == 1024
    if (t <= L_WALK) s_nn[t] = (t == 0) ? E_EDGES : 0;
    for (int n = t; n < N_NODES; n += BLOCK) s_head[n] = -1;
    __syncthreads();

    // ---- phase 2: chained bucket build (successors of c live in head[src_c],
    //      i.e. edges b with dst_b == src_c) ----
    const int e0 = 2 * t, e1 = 2 * t + 1;
    {
        int prev0 = atomicExch(&s_head[de2.x], e0);
        s_node[e0] = (u64)se2.x | ((u64)de2.x << 12) | ((u64)(prev0 & 0xFFF) << 36);
        int prev1 = atomicExch(&s_head[de2.y], e1);
        s_node[e1] = (u64)se2.y | ((u64)de2.y << 12) | ((u64)(prev1 & 0xFFF) << 36);
    }
    __syncthreads();

    // ---- phase 3: embed hs = head[src_e]; then level-0 frontier (aliases head) ----
    const int h0 = s_head[se2.x] & 0xFFF;
    const int h1 = s_head[se2.y] & 0xFFF;
    s_node[e0] |= (u64)h0 << 24;
    s_node[e1] |= (u64)h1 << 24;
    __syncthreads();                        // all head reads done; bufA reusable
    s_bufA[e0] = (u64)e0 | ((u64)de2.x << 11) | ((u64)h0 << 23) | ((u64)ge2.x << 35);
    s_bufA[e1] = (u64)e1 | ((u64)de2.y << 11) | ((u64)h1 << 23) | ((u64)ge2.y << 35);
    __syncthreads();

    // ---- BFS levels 0..7: walk chain, one ds_read_b64 per candidate ----
    u64* cur = s_bufA;
    u64* nxt = s_bufB;
    for (int d = 0; d < L_WALK; ++d) {
        int n_cur = s_nn[d];
        if (n_cur > CAP) n_cur = CAP;
        for (int idx = t; idx < n_cur; idx += BLOCK) {
            u64 e = cur[idx];
            int s   = (int)( e        & 0x7FF);
            int dcc = (int)((e >> 11) & 0xFFF);
            int ptr = (int)((e >> 23) & 0xFFF);
            u64 gb  = e & (0x7Full << 35);
            while (ptr != 0xFFF) {
                u64 q = s_node[ptr];
                int sb = (int)(q & 0xFFF);
                int nx = (int)((q >> 36) & 0xFFF);
                if (sb != dcc) {                         // non-backtracking
                    if (ptr == s)
                        atomicAdd(&s_sig[(int)(gb >> 35) * L_WALK + d], 1);
                    if (d < L_WALK - 1) {
                        u64 e2 = (u64)s | (((q >> 12) & 0xFFFFFFull) << 11) | gb;
                        u64 m = __ballot(1);
                        int leader = __ffsll(m) - 1;
                        int rank   = __popcll(m & ((1ull << lane) - 1ull));
                        int bpos = 0;
                        if (lane == leader) bpos = atomicAdd(&s_nn[d + 1], (int)__popcll(m));
                        bpos = __shfl(bpos, leader);
                        if (bpos + rank < CAP) nxt[bpos + rank] = e2;
                    }
                }
                ptr = nx;
            }
        }
        u64* tmp = cur; cur = nxt; nxt = tmp;
        __syncthreads();
    }

    // ---- MLP (identical arithmetic to R4; weights/sig all in LDS) ----
    float* s_part = (float*)s_node;         // s_node dead after BFS
    {
        const int g   = t >> 3;
        const int sub = t & 7;
        float sv[L_WALK];
        #pragma unroll
        for (int k = 0; k < L_WALK; ++k) sv[k] = (float)s_sig[g * L_WALK + k];
        float o = 0.0f;
        const int j0 = sub * 16;
        #pragma unroll 4
        for (int jj = 0; jj < 16; ++jj) {
            int j = j0 + jj;
            float a = s_b1[j];
            #pragma unroll
            for (int k = 0; k < L_WALK; ++k) a += sv[k] * s_W1[k * HID + j];
            o += fmaxf(a, 0.0f) * s_W2[j];
        }
        s_part[t] = o;
    }
    __syncthreads();
    if (t < G_GRAPHS) {
        float r = s_b2;
        #pragma unroll
        for (int s = 0; s < 8; ++s) r += s_part[t * 8 + s];
        out[t] = r;
    }
}

extern "C" void kernel_launch(void* const* d_in, const int* in_sizes, int n_in,
                              void* d_out, int out_size, void* d_ws, size_t ws_size,
                              hipStream_t stream) {
    const int*   edge_index = (const int*)d_in[0];
    const int*   edge_graph = (const int*)d_in[1];
    const float* W1 = (const float*)d_in[2];
    const float* b1 = (const float*)d_in[3];
    const float* W2 = (const float*)d_in[4];
    const float* b2 = (const float*)d_in[5];
    float* out = (float*)d_out;

    nbc_all<<<1, BLOCK, 0, stream>>>(edge_index, edge_graph, W1, b1, W2, b2, out);
}